// Round 6
// baseline (86.430 us; speedup 1.0000x reference)
//
#include <hip/hip_runtime.h>
#include <math.h>

#define N      2048
#define B      8
#define NROW   16            // 8 pred rows + 8 target rows
#define CHUNKS 16
#define EPB    128           // elements counted per block
#define NT     512

typedef unsigned long long u64;
typedef unsigned int       u32;

// ws layout (4-byte units):
//   pos    int   [NROW][N] @ 0
//   ranks  float [NROW][N] @ NROW*N
//   ticket int   [NROW+1]  @ 2*NROW*N   (rowcnt[16], gridcnt)
#define WS_POS    0
#define WS_RANKS  (NROW * N)
#define WS_TICKET (2 * NROW * N)

__device__ inline u32 f2key(float f) {
    u32 u = __float_as_uint(f);
    return (u & 0x80000000u) ? ~u : (u | 0x80000000u);
}
__device__ inline float key2f(u32 u) {
    u = (u & 0x80000000u) ? (u & 0x7fffffffu) : ~u;
    return __uint_as_float(u);
}
__device__ inline double wave_red(double v) {
#pragma unroll
    for (int o = 32; o > 0; o >>= 1) v += __shfl_down(v, o, 64);
    return v;
}

// Phase-disjoint LDS overlays:
//  a: counting phase   — keys [0,16K), scnt [16K,18K)
//  b: PAVA phase       — bsum [0,16K) (clobbers dead keys), sv [16K,24K),
//                        bcnt [24K,32K), nb [32K,34K)
//  c: correlation      — sh [0,64)
union SMem {
    struct { u64 keys[N]; u32 scnt[NT]; } a;
    struct { double bsum[N]; float sv[N]; int bcnt[N]; int nb[NT]; } b;
    struct { double sh[B]; } c;
};

__global__ __launch_bounds__(NT) void spearman_fused_kernel(
        const float* __restrict__ pred, const float* __restrict__ target,
        float* __restrict__ out, float* __restrict__ ws) {
    __shared__ SMem sm;
    __shared__ int  flag_sh;
    __shared__ int  nf_sh;

    const int t  = threadIdx.x;
    const int rr = blockIdx.x >> 4;    // row 0..15
    const int ch = blockIdx.x & 15;    // chunk 0..15
    const float* row = (rr < B) ? pred + (size_t)rr * N
                                : target + (size_t)(rr - B) * N;
    int*   posg   = (int*)ws + WS_POS;
    float* ranksg = ws + WS_RANKS;
    int*   ticket = (int*)ws + WS_TICKET;

    // ---- phase A: stage u64 keys (value<<32 | index: strict total order,
    // tie-exact) and counting-rank this block's 128 elements.
    {
        const float4 v = *(const float4*)(row + t * 4);
        const int g = t * 4;
        sm.a.keys[g + 0] = ((u64)f2key(v.x) << 32) | (u32)(g + 0);
        sm.a.keys[g + 1] = ((u64)f2key(v.y) << 32) | (u32)(g + 1);
        sm.a.keys[g + 2] = ((u64)f2key(v.z) << 32) | (u32)(g + 2);
        sm.a.keys[g + 3] = ((u64)f2key(v.w) << 32) | (u32)(g + 3);
    }
    __syncthreads();
    {
        const int e  = t & (EPB - 1);      // element within chunk
        const int h  = t >> 7;             // quarter 0..3
        const int gi = ch * EPB + e;
        const u64 Ki = sm.a.keys[gi];
        u32 cnt = 0;
        const int j0 = h * (N / 4);
#pragma unroll 8
        for (int j = j0; j < j0 + N / 4; ++j)
            cnt += (sm.a.keys[j] > Ki) ? 1u : 0u;
        sm.a.scnt[t] = cnt;
    }
    __syncthreads();
    if (t < EPB) {
        const u32 p = sm.a.scnt[t] + sm.a.scnt[t + 128]
                    + sm.a.scnt[t + 256] + sm.a.scnt[t + 384];
        posg[rr * N + ch * EPB + t] = (int)p;   // descending position, unique
    }

    // ---- row ticket: last chunk block of this row becomes the finisher
    __threadfence();
    __syncthreads();
    if (t == 0) flag_sh = (atomicAdd(&ticket[rr], 1) == CHUNKS - 1) ? 1 : 0;
    __syncthreads();
    if (!flag_sh) return;
    __threadfence();                       // acquire: see peers' pos writes

    // ---- finisher: gather pos, scatter sorted values into LDS.
    // (keys still live in this block's LDS; sv region doesn't overlap keys.)
    int   pos4[4];
    float v4[4];
    {
        const int i0 = t * 4;
        const int4 p4 = *(const int4*)(posg + rr * N + i0);
        pos4[0] = p4.x; pos4[1] = p4.y; pos4[2] = p4.z; pos4[3] = p4.w;
#pragma unroll
        for (int e = 0; e < 4; ++e)
            v4[e] = key2f((u32)(sm.a.keys[i0 + e] >> 32));
#pragma unroll
        for (int e = 0; e < 4; ++e)
            sm.b.sv[pos4[e]] = v4[e];
    }
    __syncthreads();   // all keys reads + sv writes done before bsum clobbers

    // ---- PAVA phase 1: local non-increasing fit on own 4 sorted elements.
    // y[g] = s[g] - (N - g); block sums exact in double.
    {
        const int base = t * 4;
        int m = 0;
#pragma unroll
        for (int e = 0; e < 4; ++e) {
            const int g = base + e;
            double s = (double)sm.b.sv[g] - (double)(N - g);
            int q = 1;
            while (m > 0) {
                const double ps = sm.b.bsum[base + m - 1];
                const int    pq = sm.b.bcnt[base + m - 1];
                if (ps * (double)q < s * (double)pq) { s += ps; q += pq; --m; }
                else break;
            }
            sm.b.bsum[base + m] = s; sm.b.bcnt[base + m] = q; ++m;
        }
        sm.b.nb[t] = m;
    }

    // ---- PAVA phase 2: parallel tree merge (9 levels), all in LDS
    for (int l = 0; l < 9; ++l) {
        __syncthreads();
        const int pairs = NT >> (l + 1);
        if (t < pairs) {
            const int W  = 1 << l;
            const int c  = t << (l + 1);
            const int lb = c * 4;
            const int rb = (c + W) * 4;
            int m = sm.b.nb[c];
            const int rn = sm.b.nb[c + W];
            for (int x = 0; x < rn; ++x) {
                double s = sm.b.bsum[rb + x]; int q = sm.b.bcnt[rb + x];
                while (m > 0) {
                    const double ps = sm.b.bsum[lb + m - 1];
                    const int    pq = sm.b.bcnt[lb + m - 1];
                    if (ps * (double)q < s * (double)pq) { s += ps; q += pq; --m; }
                    else break;
                }
                sm.b.bsum[lb + m] = s; sm.b.bcnt[lb + m] = q; ++m;
            }
            sm.b.nb[c] = m;
        }
    }
    __syncthreads();

    // ---- compact: bcnt -> block starts, low floats of bsum -> means
    if (t == 0) {
        const int m = sm.b.nb[0];
        float* bm = (float*)sm.b.bsum;
        int st = 0;
        for (int f = 0; f < m; ++f) {
            const int    cq = sm.b.bcnt[f];
            const double s  = sm.b.bsum[f];
            sm.b.bcnt[f] = st;
            bm[f] = (float)(s / (double)cq);
            st += cq;
        }
        nf_sh = m;
    }
    __syncthreads();

    // ---- rank write: binary search in LDS (m tiny), coalesced float4 store
    {
        const int m = nf_sh;
        const float* bm = (const float*)sm.b.bsum;
        float r4[4];
#pragma unroll
        for (int e = 0; e < 4; ++e) {
            const int p = pos4[e];
            int lo = 0, hi = m - 1;
            while (lo < hi) {               // last f with bstart[f] <= p
                const int mid = (lo + hi + 1) >> 1;
                if (sm.b.bcnt[mid] <= p) lo = mid; else hi = mid - 1;
            }
            r4[e] = v4[e] - bm[lo];
        }
        const float4 o4 = {r4[0], r4[1], r4[2], r4[3]};
        *(float4*)(ranksg + (size_t)rr * N + t * 4) = o4;
    }

    // ---- grid ticket: last row-finisher does the correlation
    __threadfence();
    __syncthreads();
    if (t == 0) flag_sh = (atomicAdd(&ticket[NROW], 1) == NROW - 1) ? 1 : 0;
    __syncthreads();
    if (!flag_sh) return;
    __threadfence();                       // acquire: see peers' rank rows

    // ---- Pearson correlation: wave w handles batch w, float4 streams
    {
        const int w = t >> 6, lane = t & 63;
        const float* rp = ranksg + (size_t)w * N;
        const float* rt = ranksg + (size_t)(w + B) * N;
        double sp = 0, st = 0, spp = 0, stt = 0, spt = 0;
#pragma unroll
        for (int i2 = 0; i2 < (N / 4) / 64; ++i2) {
            const float4 a = ((const float4*)rp)[lane + i2 * 64];
            const float4 c = ((const float4*)rt)[lane + i2 * 64];
            const double ax = a.x, ay = a.y, az = a.z, aw = a.w;
            const double cx = c.x, cy = c.y, cz = c.z, cw = c.w;
            sp  += ax + ay + az + aw;
            st  += cx + cy + cz + cw;
            spp += ax * ax + ay * ay + az * az + aw * aw;
            stt += cx * cx + cy * cy + cz * cz + cw * cw;
            spt += ax * cx + ay * cy + az * cz + aw * cw;
        }
        sp  = wave_red(sp);  st  = wave_red(st);
        spp = wave_red(spp); stt = wave_red(stt); spt = wave_red(spt);
        __syncthreads();   // b-phase LDS reads done before sh overlay
        if (lane == 0) {
            const double n   = (double)N;
            const double cv  = spt - sp * st / n;
            const double vp2 = spp - sp * sp / n;
            const double vt2 = stt - st * st / n;
            sm.c.sh[w] = cv / (sqrt(vp2) * sqrt(vt2) + 1e-8);
        }
        __syncthreads();
        if (t == 0) {
            double s = 0.0;
            for (int i = 0; i < B; ++i) s += sm.c.sh[i];
            out[0] = (float)(1.0 - s / (double)B);
        }
    }
}

extern "C" void kernel_launch(void* const* d_in, const int* in_sizes, int n_in,
                              void* d_out, int out_size, void* d_ws, size_t ws_size,
                              hipStream_t stream) {
    const float* pred   = (const float*)d_in[0];
    const float* target = (const float*)d_in[1];
    float* out = (float*)d_out;
    float* ws  = (float*)d_ws;

    // zero the 17 ticket counters (graph-capture-safe stream op; keeps every
    // replay deterministic)
    hipMemsetAsync((char*)d_ws + (size_t)WS_TICKET * 4, 0,
                   (NROW + 1) * sizeof(int), stream);
    spearman_fused_kernel<<<NROW * CHUNKS, NT, 0, stream>>>(pred, target, out, ws);
}

// Round 7
// 26.063 us; speedup vs baseline: 3.3162x; 3.3162x over previous
//
#include <hip/hip_runtime.h>
#include <math.h>

#define N      2048
#define B      8
#define NROW   16            // 8 pred rows + 8 target rows
#define CHUNKS 16
#define EPB    128           // elements ranked per K1 block
#define K1T    512
#define K2T    512
#define HALF   256           // K2 threads per row
#define EPT    8             // K2 elements per thread

typedef unsigned long long u64;
typedef unsigned int       u32;

// ws layout (bytes): pos int[NROW][N] @0 (128 KB); corrd double[B] @128 KB
#define WS_CORRD_OFF (NROW * N * sizeof(int))

__device__ inline u32 f2key(float f) {
    u32 u = __float_as_uint(f);
    return (u & 0x80000000u) ? ~u : (u | 0x80000000u);
}
__device__ inline double wave_red(double v) {
#pragma unroll
    for (int o = 32; o > 0; o >>= 1) v += __shfl_down(v, o, 64);
    return v;
}

// K1: counting rank. Block = (row, chunk of 128). Stage row's u64 keys
// (value<<32 | index: strict total order, tie-exact — ties provably land in
// the same PAVA block so tie order cannot change the output) in LDS; 4
// threads per element count "greater" over one quarter (broadcast reads).
__global__ __launch_bounds__(K1T) void count_pos_kernel(
        const float* __restrict__ pred, const float* __restrict__ target,
        int* __restrict__ posg) {
    __shared__ u64 keys[N];
    __shared__ u32 scnt[K1T];

    const int t  = threadIdx.x;
    const int rr = blockIdx.x >> 4;
    const int ch = blockIdx.x & 15;
    const float* row = (rr < B) ? pred + (size_t)rr * N
                                : target + (size_t)(rr - B) * N;

    {
        const float4 v = *(const float4*)(row + t * 4);
        const int g = t * 4;
        keys[g + 0] = ((u64)f2key(v.x) << 32) | (u32)(g + 0);
        keys[g + 1] = ((u64)f2key(v.y) << 32) | (u32)(g + 1);
        keys[g + 2] = ((u64)f2key(v.z) << 32) | (u32)(g + 2);
        keys[g + 3] = ((u64)f2key(v.w) << 32) | (u32)(g + 3);
    }
    __syncthreads();
    {
        const int e  = t & (EPB - 1);
        const int h  = t >> 7;
        const u64 Ki = keys[ch * EPB + e];
        u32 cnt = 0;
        const int j0 = h * (N / 4);
#pragma unroll 8
        for (int j = j0; j < j0 + N / 4; ++j)
            cnt += (keys[j] > Ki) ? 1u : 0u;
        scnt[t] = cnt;
    }
    __syncthreads();
    if (t < EPB) {
        const u32 p = scnt[t] + scnt[t + 128] + scnt[t + 256] + scnt[t + 384];
        posg[rr * N + ch * EPB + t] = (int)p;    // descending position, unique
    }
}

// K2: block b = batch b. Threads [0,256) process the pred row, [256,512) the
// target row, concurrently. All PAVA + rank + correlation work in LDS.
__global__ __launch_bounds__(K2T) void pava_rank_corr_kernel(
        const float* __restrict__ pred, const float* __restrict__ target,
        const int* __restrict__ posg, double* __restrict__ corrd) {
    __shared__ float  sv[2][N];        // sorted values
    __shared__ double bsum[2][N];      // PAVA block sums; aliased float* means
    __shared__ int    bcnt[2][N];      // PAVA block counts -> block starts
    __shared__ int    nb[2][HALF];
    __shared__ int    nf_sh[2];
    __shared__ float  rank[2][N];
    __shared__ double redA[8], redB[8], redC[8], redD[8], redE[8];

    const int t  = threadIdx.x;
    const int r  = t >> 8;             // 0 = pred, 1 = target
    const int tt = t & (HALF - 1);
    const int b  = blockIdx.x;

    const float* row = (r == 0 ? pred : target) + (size_t)b * N;
    const int*   pos = posg + (size_t)(r == 0 ? b : b + B) * N;

    // load 8 values + 8 positions (coalesced), scatter sorted values to LDS
    float v8[EPT]; int p8[EPT];
    {
        const int i0 = tt * EPT;
        const float4 va = *(const float4*)(row + i0);
        const float4 vb = *(const float4*)(row + i0 + 4);
        v8[0]=va.x; v8[1]=va.y; v8[2]=va.z; v8[3]=va.w;
        v8[4]=vb.x; v8[5]=vb.y; v8[6]=vb.z; v8[7]=vb.w;
        const int4 pa = *(const int4*)(pos + i0);
        const int4 pb = *(const int4*)(pos + i0 + 4);
        p8[0]=pa.x; p8[1]=pa.y; p8[2]=pa.z; p8[3]=pa.w;
        p8[4]=pb.x; p8[5]=pb.y; p8[6]=pb.z; p8[7]=pb.w;
#pragma unroll
        for (int e = 0; e < EPT; ++e) sv[r][p8[e]] = v8[e];
    }
    __syncthreads();

    // PAVA phase 1: local non-increasing fit on own 8 sorted elements.
    // y[g] = s[g] - (N - g); block sums exact in double.
    {
        const int base = tt * EPT;
        int m = 0;
#pragma unroll
        for (int e = 0; e < EPT; ++e) {
            const int g = base + e;
            double s = (double)sv[r][g] - (double)(N - g);
            int q = 1;
            while (m > 0) {
                const double ps = bsum[r][base + m - 1];
                const int    pq = bcnt[r][base + m - 1];
                if (ps * (double)q < s * (double)pq) { s += ps; q += pq; --m; }
                else break;
            }
            bsum[r][base + m] = s; bcnt[r][base + m] = q; ++m;
        }
        nb[r][tt] = m;
    }

    // PAVA phase 2: parallel tree merge (8 levels over 256 chunks of 8)
    for (int l = 0; l < 8; ++l) {
        __syncthreads();
        const int pairs = HALF >> (l + 1);
        if (tt < pairs) {
            const int W  = 1 << l;
            const int c  = tt << (l + 1);
            const int lb = c * EPT;
            const int rb = (c + W) * EPT;
            int m = nb[r][c];
            const int rn = nb[r][c + W];
            for (int x = 0; x < rn; ++x) {
                double s = bsum[r][rb + x]; int q = bcnt[r][rb + x];
                while (m > 0) {
                    const double ps = bsum[r][lb + m - 1];
                    const int    pq = bcnt[r][lb + m - 1];
                    if (ps * (double)q < s * (double)pq) { s += ps; q += pq; --m; }
                    else break;
                }
                bsum[r][lb + m] = s; bcnt[r][lb + m] = q; ++m;
            }
            nb[r][c] = m;
        }
    }
    __syncthreads();

    // compact: bcnt -> block starts, low floats of bsum -> means
    if (tt == 0) {
        const int m = nb[r][0];
        float* bm = (float*)&bsum[r][0];
        int st = 0;
        for (int f = 0; f < m; ++f) {
            const int    cq = bcnt[r][f];
            const double s  = bsum[r][f];
            bcnt[r][f] = st;
            bm[f] = (float)(s / (double)cq);
            st += cq;
        }
        nf_sh[r] = m;
    }
    __syncthreads();

    // ranks: LDS binary search (m tiny); rank[r][i0+e] contiguous writes
    {
        const int m = nf_sh[r];
        const float* bm = (const float*)&bsum[r][0];
        const int i0 = tt * EPT;
#pragma unroll
        for (int e = 0; e < EPT; ++e) {
            const int p = p8[e];
            int lo = 0, hi = m - 1;
            while (lo < hi) {                  // last f with bstart[f] <= p
                const int mid = (lo + hi + 1) >> 1;
                if (bcnt[r][mid] <= p) lo = mid; else hi = mid - 1;
            }
            rank[r][i0 + e] = v8[e] - bm[lo];
        }
    }
    __syncthreads();

    // Pearson correlation of rank[0] vs rank[1] (one-pass centered at end,
    // double accumulators; deterministic order)
    double sp = 0, st = 0, spp = 0, stt = 0, spt = 0;
    for (int i = t; i < N; i += K2T) {
        const double a = (double)rank[0][i];
        const double c = (double)rank[1][i];
        sp += a; st += c; spp += a * a; stt += c * c; spt += a * c;
    }
    sp  = wave_red(sp);  st  = wave_red(st);
    spp = wave_red(spp); stt = wave_red(stt); spt = wave_red(spt);
    const int w = t >> 6, lane = t & 63;
    if (lane == 0) { redA[w]=sp; redB[w]=st; redC[w]=spp; redD[w]=stt; redE[w]=spt; }
    __syncthreads();
    if (t == 0) {
        double a=0, c=0, aa=0, cc=0, ac=0;
        for (int i = 0; i < 8; ++i) { a+=redA[i]; c+=redB[i]; aa+=redC[i]; cc+=redD[i]; ac+=redE[i]; }
        const double n   = (double)N;
        const double cv  = ac - a * c / n;
        const double vp2 = aa - a * a / n;
        const double vt2 = cc - c * c / n;
        corrd[b] = cv / (sqrt(vp2) * sqrt(vt2) + 1e-8);
    }
}

__global__ void finalize_kernel(const double* __restrict__ corrd,
                                float* __restrict__ out) {
    if (threadIdx.x == 0 && blockIdx.x == 0) {
        double s = 0.0;
        for (int i = 0; i < B; ++i) s += corrd[i];
        out[0] = (float)(1.0 - s / (double)B);
    }
}

extern "C" void kernel_launch(void* const* d_in, const int* in_sizes, int n_in,
                              void* d_out, int out_size, void* d_ws, size_t ws_size,
                              hipStream_t stream) {
    const float* pred   = (const float*)d_in[0];
    const float* target = (const float*)d_in[1];
    float*  out   = (float*)d_out;
    int*    posg  = (int*)d_ws;
    double* corrd = (double*)((char*)d_ws + WS_CORRD_OFF);

    count_pos_kernel<<<NROW * CHUNKS, K1T, 0, stream>>>(pred, target, posg);
    pava_rank_corr_kernel<<<B, K2T, 0, stream>>>(pred, target, posg, corrd);
    finalize_kernel<<<1, 64, 0, stream>>>(corrd, out);
}

// Round 8
// 23.473 us; speedup vs baseline: 3.6820x; 1.1103x over previous
//
#include <hip/hip_runtime.h>
#include <math.h>

#define N      2048
#define B      8
#define NROW   16            // 8 pred rows + 8 target rows
#define CHUNKS 16
#define EPB    128           // elements ranked per K1 block
#define K1T    512
#define K2T    512
#define HALF   256           // K2 threads per row
#define EPT    8             // K2 elements per thread (256 chunks -> 8 levels)

typedef unsigned long long u64;
typedef unsigned int       u32;

// ws layout (4-byte units): pos int[NROW][N] @0 ; sv float[NROW][N] @NROW*N
#define WS_POS 0
#define WS_SV  (NROW * N)

__device__ inline u32 f2key(float f) {
    u32 u = __float_as_uint(f);
    return (u & 0x80000000u) ? ~u : (u | 0x80000000u);
}
__device__ inline float key2f(u32 u) {
    u = (u & 0x80000000u) ? (u & 0x7fffffffu) : ~u;
    return __uint_as_float(u);
}
__device__ inline double wave_red(double v) {
#pragma unroll
    for (int o = 32; o > 0; o >>= 1) v += __shfl_down(v, o, 64);
    return v;
}

// K1: counting rank. Block = (row, chunk of 128). Stage row's u64 keys
// (value<<32 | index: strict total order, tie-exact — ties provably pool into
// the same PAVA block, so tie order cannot change the output) in LDS; 4
// threads per element count "greater" over one quarter (wave-uniform
// broadcast reads). Writes pos[row][i] and scatters sv[row][pos]=value.
// Block 0 also (re)initializes out[0]=1.0 for K2's atomic finalize.
__global__ __launch_bounds__(K1T) void count_pos_kernel(
        const float* __restrict__ pred, const float* __restrict__ target,
        int* __restrict__ posg, float* __restrict__ svg,
        float* __restrict__ out) {
    __shared__ u64 keys[N];
    __shared__ u32 scnt[K1T];

    const int t  = threadIdx.x;
    const int rr = blockIdx.x >> 4;
    const int ch = blockIdx.x & 15;
    const float* row = (rr < B) ? pred + (size_t)rr * N
                                : target + (size_t)(rr - B) * N;

    if (blockIdx.x == 0 && t == 0) out[0] = 1.0f;

    {
        const float4 v = *(const float4*)(row + t * 4);
        const int g = t * 4;
        keys[g + 0] = ((u64)f2key(v.x) << 32) | (u32)(g + 0);
        keys[g + 1] = ((u64)f2key(v.y) << 32) | (u32)(g + 1);
        keys[g + 2] = ((u64)f2key(v.z) << 32) | (u32)(g + 2);
        keys[g + 3] = ((u64)f2key(v.w) << 32) | (u32)(g + 3);
    }
    __syncthreads();
    {
        const int e  = t & (EPB - 1);
        const int h  = t >> 7;
        const u64 Ki = keys[ch * EPB + e];
        u32 cnt = 0;
        const int j0 = h * (N / 4);
#pragma unroll 8
        for (int j = j0; j < j0 + N / 4; ++j)
            cnt += (keys[j] > Ki) ? 1u : 0u;
        scnt[t] = cnt;
    }
    __syncthreads();
    if (t < EPB) {
        const u32 p = scnt[t] + scnt[t + 128] + scnt[t + 256] + scnt[t + 384];
        const u64 Ki = keys[ch * EPB + t];
        posg[rr * N + ch * EPB + t] = (int)p;          // descending pos, unique
        svg[rr * N + (int)p] = key2f((u32)(Ki >> 32)); // sorted values
    }
}

// K2: block b = batch b. Threads [0,256) = pred row, [256,512) = target row.
// Loads sorted values coalesced from global, exact PAVA (local EPT=8 fit +
// 8-level tree merge, double sums) in LDS, ranks via tiny LDS binary search,
// Pearson correlation, then atomicAdd(-corr/B) into out (K1 set out=1).
__global__ __launch_bounds__(K2T) void pava_rank_corr_kernel(
        const float* __restrict__ pred, const float* __restrict__ target,
        const int* __restrict__ posg, const float* __restrict__ svg,
        float* __restrict__ out) {
    __shared__ double bsum[2][N];      // PAVA block sums; aliased float* means
    __shared__ int    bcnt[2][N];      // PAVA block counts -> block starts
    __shared__ int    nb[2][HALF];
    __shared__ int    nf_sh[2];
    __shared__ float  rankt[N];        // target-row ranks (original order)
    __shared__ double red[5][4];

    const int t  = threadIdx.x;
    const int r  = t >> 8;             // 0 = pred, 1 = target
    const int tt = t & (HALF - 1);
    const int b  = blockIdx.x;
    const int rowid = (r == 0) ? b : b + B;
    const int i0 = tt * EPT;

    // PAVA phase 1: local non-increasing fit on own 8 sorted elements,
    // loaded coalesced from global. y[g] = s[g] - (N - g); sums in double.
    {
        const float* svrow = svg + (size_t)rowid * N;
        const float4 sa = *(const float4*)(svrow + i0);
        const float4 sb = *(const float4*)(svrow + i0 + 4);
        const float s8[EPT] = {sa.x, sa.y, sa.z, sa.w, sb.x, sb.y, sb.z, sb.w};
        int m = 0;
#pragma unroll
        for (int e = 0; e < EPT; ++e) {
            const int g = i0 + e;
            double s = (double)s8[e] - (double)(N - g);
            int q = 1;
            while (m > 0) {
                const double ps = bsum[r][i0 + m - 1];
                const int    pq = bcnt[r][i0 + m - 1];
                if (ps * (double)q < s * (double)pq) { s += ps; q += pq; --m; }
                else break;
            }
            bsum[r][i0 + m] = s; bcnt[r][i0 + m] = q; ++m;
        }
        nb[r][tt] = m;
    }

    // PAVA phase 2: parallel tree merge (8 levels over 256 chunks of 8)
    for (int l = 0; l < 8; ++l) {
        __syncthreads();
        const int pairs = HALF >> (l + 1);
        if (tt < pairs) {
            const int W  = 1 << l;
            const int c  = tt << (l + 1);
            const int lb = c * EPT;
            const int rb = (c + W) * EPT;
            int m = nb[r][c];
            const int rn = nb[r][c + W];
            for (int x = 0; x < rn; ++x) {
                double s = bsum[r][rb + x]; int q = bcnt[r][rb + x];
                while (m > 0) {
                    const double ps = bsum[r][lb + m - 1];
                    const int    pq = bcnt[r][lb + m - 1];
                    if (ps * (double)q < s * (double)pq) { s += ps; q += pq; --m; }
                    else break;
                }
                bsum[r][lb + m] = s; bcnt[r][lb + m] = q; ++m;
            }
            nb[r][c] = m;
        }
    }
    __syncthreads();

    // compact: bcnt -> block starts, low floats of bsum -> means
    // (write at byte 4f stays below unread double at byte 8f: exact-safe)
    if (tt == 0) {
        const int m = nb[r][0];
        float* bm = (float*)&bsum[r][0];
        int st = 0;
        for (int f = 0; f < m; ++f) {
            const int    cq = bcnt[r][f];
            const double s  = bsum[r][f];
            bcnt[r][f] = st;
            bm[f] = (float)(s / (double)cq);
            st += cq;
        }
        nf_sh[r] = m;
    }
    __syncthreads();

    // ranks for own 8 original-order elements: value - bmean[block(pos)]
    float r8[EPT];
    {
        const float* row = (r == 0 ? pred : target) + (size_t)b * N;
        const int*   pos = posg + (size_t)rowid * N;
        const float4 va = *(const float4*)(row + i0);
        const float4 vb = *(const float4*)(row + i0 + 4);
        const float v8[EPT] = {va.x, va.y, va.z, va.w, vb.x, vb.y, vb.z, vb.w};
        const int4 pa = *(const int4*)(pos + i0);
        const int4 pb = *(const int4*)(pos + i0 + 4);
        const int p8[EPT] = {pa.x, pa.y, pa.z, pa.w, pb.x, pb.y, pb.z, pb.w};
        const int m = nf_sh[r];
        const float* bm = (const float*)&bsum[r][0];
#pragma unroll
        for (int e = 0; e < EPT; ++e) {
            const int p = p8[e];
            int lo = 0, hi = m - 1;
            while (lo < hi) {                  // last f with bstart[f] <= p
                const int mid = (lo + hi + 1) >> 1;
                if (bcnt[r][mid] <= p) lo = mid; else hi = mid - 1;
            }
            r8[e] = v8[e] - bm[lo];
        }
    }
    if (r == 1) {
#pragma unroll
        for (int e = 0; e < EPT; ++e) rankt[i0 + e] = r8[e];
    }
    __syncthreads();

    // Pearson: pred-half threads pair their register ranks with the target
    // ranks at the same original indices from LDS. 4-wave reduction.
    if (r == 0) {
        double sp = 0, st = 0, spp = 0, stt = 0, spt = 0;
#pragma unroll
        for (int e = 0; e < EPT; ++e) {
            const double a = (double)r8[e];
            const double c = (double)rankt[i0 + e];
            sp += a; st += c; spp += a * a; stt += c * c; spt += a * c;
        }
        sp  = wave_red(sp);  st  = wave_red(st);
        spp = wave_red(spp); stt = wave_red(stt); spt = wave_red(spt);
        const int w = t >> 6, lane = t & 63;
        if (lane == 0) {
            red[0][w] = sp; red[1][w] = st; red[2][w] = spp;
            red[3][w] = stt; red[4][w] = spt;
        }
    }
    __syncthreads();
    if (t == 0) {
        double a = 0, c = 0, aa = 0, cc = 0, ac = 0;
        for (int i = 0; i < 4; ++i) {
            a += red[0][i]; c += red[1][i]; aa += red[2][i];
            cc += red[3][i]; ac += red[4][i];
        }
        const double n   = (double)N;
        const double cv  = ac - a * c / n;
        const double vp2 = aa - a * a / n;
        const double vt2 = cc - c * c / n;
        const double corr = cv / (sqrt(vp2) * sqrt(vt2) + 1e-8);
        atomicAdd(out, (float)(-corr / (double)B));
    }
}

extern "C" void kernel_launch(void* const* d_in, const int* in_sizes, int n_in,
                              void* d_out, int out_size, void* d_ws, size_t ws_size,
                              hipStream_t stream) {
    const float* pred   = (const float*)d_in[0];
    const float* target = (const float*)d_in[1];
    float* out  = (float*)d_out;
    int*   posg = (int*)d_ws + WS_POS;
    float* svg  = (float*)d_ws + WS_SV;

    count_pos_kernel<<<NROW * CHUNKS, K1T, 0, stream>>>(pred, target, posg, svg, out);
    pava_rank_corr_kernel<<<B, K2T, 0, stream>>>(pred, target, posg, svg, out);
}

// Round 9
// 21.110 us; speedup vs baseline: 4.0944x; 1.1120x over previous
//
#include <hip/hip_runtime.h>
#include <math.h>

#define N      2048
#define B      8
#define NROW   16            // 8 pred rows + 8 target rows
#define CHUNKS 32
#define EPB    64            // elements ranked per K1 block
#define K1T    512
#define K2T    512
#define HALF   256           // K2 threads per row
#define EPT    8             // K2 elements per thread (256 chunks -> 8 levels)

typedef unsigned long long u64;
typedef unsigned int       u32;

// ws layout (4-byte units): pos int[NROW][N] @0 ; sv float[NROW][N] @NROW*N
#define WS_POS 0
#define WS_SV  (NROW * N)

__device__ inline u32 f2key(float f) {
    u32 u = __float_as_uint(f);
    return (u & 0x80000000u) ? ~u : (u | 0x80000000u);
}
__device__ inline float key2f(u32 u) {
    u = (u & 0x80000000u) ? (u & 0x7fffffffu) : ~u;
    return __uint_as_float(u);
}
__device__ inline double wave_red(double v) {
#pragma unroll
    for (int o = 32; o > 0; o >>= 1) v += __shfl_down(v, o, 64);
    return v;
}

// K1: counting rank. Block = (row, chunk of 64). Stage row's u64 keys
// (value<<32 | index: strict total order, tie-exact — ties provably pool into
// the same PAVA block, so tie order cannot change the output) in LDS; 8
// threads per element count "greater" over one eighth (wave-uniform broadcast
// reads, pairwise to widen LDS access). Writes pos[row][i], sv[row][pos]=v.
// Block 0 also (re)initializes out[0]=1.0 for K2's atomic finalize.
__global__ __launch_bounds__(K1T) void count_pos_kernel(
        const float* __restrict__ pred, const float* __restrict__ target,
        int* __restrict__ posg, float* __restrict__ svg,
        float* __restrict__ out) {
    __shared__ u64 keys[N];
    __shared__ u32 scnt[K1T];

    const int t  = threadIdx.x;
    const int rr = blockIdx.x >> 5;
    const int ch = blockIdx.x & 31;
    const float* row = (rr < B) ? pred + (size_t)rr * N
                                : target + (size_t)(rr - B) * N;

    if (blockIdx.x == 0 && t == 0) out[0] = 1.0f;

    {
        const float4 v = *(const float4*)(row + t * 4);
        const int g = t * 4;
        keys[g + 0] = ((u64)f2key(v.x) << 32) | (u32)(g + 0);
        keys[g + 1] = ((u64)f2key(v.y) << 32) | (u32)(g + 1);
        keys[g + 2] = ((u64)f2key(v.z) << 32) | (u32)(g + 2);
        keys[g + 3] = ((u64)f2key(v.w) << 32) | (u32)(g + 3);
    }
    __syncthreads();
    {
        const int e  = t & (EPB - 1);      // element within chunk
        const int h  = t >> 6;             // eighth 0..7
        const u64 Ki = keys[ch * EPB + e];
        u32 cnt = 0;
        const int j0 = h * (N / 8);
#pragma unroll 4
        for (int j = j0; j < j0 + N / 8; j += 2) {
            const u64 k0 = keys[j], k1 = keys[j + 1];
            cnt += (k0 > Ki) ? 1u : 0u;
            cnt += (k1 > Ki) ? 1u : 0u;
        }
        scnt[t] = cnt;
    }
    __syncthreads();
    if (t < EPB) {
        u32 p = 0;
#pragma unroll
        for (int k = 0; k < 8; ++k) p += scnt[t + 64 * k];
        const u64 Ki = keys[ch * EPB + t];
        posg[rr * N + ch * EPB + t] = (int)p;          // descending pos, unique
        svg[rr * N + (int)p] = key2f((u32)(Ki >> 32)); // sorted values
    }
}

// K2: block b = batch b. Threads [0,256) = pred row, [256,512) = target row.
// All global loads hoisted to the top (overlap PAVA). Exact PAVA (local EPT=8
// fit + 8-level tree merge, double sums) in LDS; merge levels >= 2 are
// wave-local (producers+consumers in the half's wave 0) -> LDS fence only.
// Ranks via tiny LDS binary search, Pearson, atomicAdd(-corr/B) into out.
__global__ __launch_bounds__(K2T) void pava_rank_corr_kernel(
        const float* __restrict__ pred, const float* __restrict__ target,
        const int* __restrict__ posg, const float* __restrict__ svg,
        float* __restrict__ out) {
    __shared__ double bsum[2][N];      // PAVA block sums; aliased float* means
    __shared__ int    bcnt[2][N];      // PAVA block counts -> block starts
    __shared__ int    nb[2][HALF];
    __shared__ int    nf_sh[2];
    __shared__ float  rankt[N];        // target-row ranks (original order)
    __shared__ double red[5][4];

    const int t  = threadIdx.x;
    const int r  = t >> 8;             // 0 = pred, 1 = target
    const int tt = t & (HALF - 1);
    const int b  = blockIdx.x;
    const int rowid = (r == 0) ? b : b + B;
    const int i0 = tt * EPT;

    // ---- hoisted global loads: sorted values, original values, positions
    const float* svrow = svg + (size_t)rowid * N;
    const float4 sa = *(const float4*)(svrow + i0);
    const float4 sb = *(const float4*)(svrow + i0 + 4);
    const float* row = (r == 0 ? pred : target) + (size_t)b * N;
    const float4 va = *(const float4*)(row + i0);
    const float4 vb = *(const float4*)(row + i0 + 4);
    const int*   pos = posg + (size_t)rowid * N;
    const int4   pa = *(const int4*)(pos + i0);
    const int4   pb = *(const int4*)(pos + i0 + 4);

    // ---- PAVA phase 1: local non-increasing fit on own 8 sorted elements.
    // y[g] = s[g] - (N - g); block sums exact in double.
    {
        const float s8[EPT] = {sa.x, sa.y, sa.z, sa.w, sb.x, sb.y, sb.z, sb.w};
        int m = 0;
#pragma unroll
        for (int e = 0; e < EPT; ++e) {
            const int g = i0 + e;
            double s = (double)s8[e] - (double)(N - g);
            int q = 1;
            while (m > 0) {
                const double ps = bsum[r][i0 + m - 1];
                const int    pq = bcnt[r][i0 + m - 1];
                if (ps * (double)q < s * (double)pq) { s += ps; q += pq; --m; }
                else break;
            }
            bsum[r][i0 + m] = s; bcnt[r][i0 + m] = q; ++m;
        }
        nb[r][tt] = m;
    }

    // ---- PAVA phase 2: tree merge, 8 levels over 256 chunks of 8.
    // Levels 0,1: producers span >1 wave -> __syncthreads. Levels >= 2:
    // active threads (tt<32) and their producers (tt<64) are both in the
    // half's wave 0 -> lockstep execution, LDS fence suffices.
    for (int l = 0; l < 8; ++l) {
        if (l < 2) __syncthreads();
        else       __threadfence_block();
        const int pairs = HALF >> (l + 1);
        if (tt < pairs) {
            const int W  = 1 << l;
            const int c  = tt << (l + 1);
            const int lb = c * EPT;
            const int rb = (c + W) * EPT;
            int m = nb[r][c];
            const int rn = nb[r][c + W];
            for (int x = 0; x < rn; ++x) {
                double s = bsum[r][rb + x]; int q = bcnt[r][rb + x];
                while (m > 0) {
                    const double ps = bsum[r][lb + m - 1];
                    const int    pq = bcnt[r][lb + m - 1];
                    if (ps * (double)q < s * (double)pq) { s += ps; q += pq; --m; }
                    else break;
                }
                bsum[r][lb + m] = s; bcnt[r][lb + m] = q; ++m;
            }
            nb[r][c] = m;
        }
    }

    // ---- compact (tt==0 is in the half's wave 0: fence suffices before)
    __threadfence_block();
    if (tt == 0) {
        const int m = nb[r][0];
        float* bm = (float*)&bsum[r][0];
        int st = 0;
        for (int f = 0; f < m; ++f) {
            const int    cq = bcnt[r][f];
            const double s  = bsum[r][f];
            bcnt[r][f] = st;
            bm[f] = (float)(s / (double)cq);
            st += cq;
        }
        nf_sh[r] = m;
    }
    __syncthreads();   // publish means/starts/m to all threads of the half

    // ---- ranks for own 8 original-order elements: v - bmean[block(pos)]
    float r8[EPT];
    {
        const float v8[EPT] = {va.x, va.y, va.z, va.w, vb.x, vb.y, vb.z, vb.w};
        const int   p8[EPT] = {pa.x, pa.y, pa.z, pa.w, pb.x, pb.y, pb.z, pb.w};
        const int m = nf_sh[r];
        const float* bm = (const float*)&bsum[r][0];
#pragma unroll
        for (int e = 0; e < EPT; ++e) {
            const int p = p8[e];
            int lo = 0, hi = m - 1;
            while (lo < hi) {                  // last f with bstart[f] <= p
                const int mid = (lo + hi + 1) >> 1;
                if (bcnt[r][mid] <= p) lo = mid; else hi = mid - 1;
            }
            r8[e] = v8[e] - bm[lo];
        }
    }
    if (r == 1) {
#pragma unroll
        for (int e = 0; e < EPT; ++e) rankt[i0 + e] = r8[e];
    }
    __syncthreads();

    // ---- Pearson: pred-half threads pair register ranks with target ranks
    // at the same original indices from LDS. 4-wave reduction.
    if (r == 0) {
        double sp = 0, st = 0, spp = 0, stt = 0, spt = 0;
#pragma unroll
        for (int e = 0; e < EPT; ++e) {
            const double a = (double)r8[e];
            const double c = (double)rankt[i0 + e];
            sp += a; st += c; spp += a * a; stt += c * c; spt += a * c;
        }
        sp  = wave_red(sp);  st  = wave_red(st);
        spp = wave_red(spp); stt = wave_red(stt); spt = wave_red(spt);
        const int w = t >> 6, lane = t & 63;
        if (lane == 0) {
            red[0][w] = sp; red[1][w] = st; red[2][w] = spp;
            red[3][w] = stt; red[4][w] = spt;
        }
    }
    __syncthreads();
    if (t == 0) {
        double a = 0, c = 0, aa = 0, cc = 0, ac = 0;
        for (int i = 0; i < 4; ++i) {
            a += red[0][i]; c += red[1][i]; aa += red[2][i];
            cc += red[3][i]; ac += red[4][i];
        }
        const double n   = (double)N;
        const double cv  = ac - a * c / n;
        const double vp2 = aa - a * a / n;
        const double vt2 = cc - c * c / n;
        const double corr = cv / (sqrt(vp2) * sqrt(vt2) + 1e-8);
        atomicAdd(out, (float)(-corr / (double)B));
    }
}

extern "C" void kernel_launch(void* const* d_in, const int* in_sizes, int n_in,
                              void* d_out, int out_size, void* d_ws, size_t ws_size,
                              hipStream_t stream) {
    const float* pred   = (const float*)d_in[0];
    const float* target = (const float*)d_in[1];
    float* out  = (float*)d_out;
    int*   posg = (int*)d_ws + WS_POS;
    float* svg  = (float*)d_ws + WS_SV;

    count_pos_kernel<<<NROW * CHUNKS, K1T, 0, stream>>>(pred, target, posg, svg, out);
    pava_rank_corr_kernel<<<B, K2T, 0, stream>>>(pred, target, posg, svg, out);
}